// Round 5
// baseline (4198.542 us; speedup 1.0000x reference)
//
#include <hip/hip_runtime.h>

// Problem:
//   r:    [N_NODES, 256] f32
//   h:    [N_EDGES, 256] f32
//   nbrs: [N_EDGES, 2]   int32 (harness converts integer inputs; dest = nbrs[e*2+0])
//   W1:   [512, 512] f32
//   W2:   [512, 256] f32
//   out = relu(concat(r, segsum(h, nbrs[:,0])) @ W1) @ W2   -> [N_NODES, 256] f32
#define F     256
#define K1    512   // 2*F
#define HDIM  512
#define FOUT  256
#define BM    32    // node rows per block
#define KT    16    // K-tile for both GEMMs

typedef float floatx4 __attribute__((ext_vector_type(4)));

// ---------------------------------------------------------------------------
// Scatter: one wave per edge row. 64 lanes x float4 = 256 floats.
// h is streamed once -> nontemporal loads keep L2 free for msg atomics.
// ---------------------------------------------------------------------------
__global__ void scatter_kernel(const floatx4* __restrict__ h4,
                               const int* __restrict__ nbrs,
                               float* msg,
                               int n_edges) {
    const int lane = threadIdx.x & 63;
    const int wid  = (int)((blockIdx.x * blockDim.x + threadIdx.x) >> 6);
    const int nw   = (int)((gridDim.x * blockDim.x) >> 6);
    for (int e = wid; e < n_edges; e += nw) {
        floatx4 v = __builtin_nontemporal_load(h4 + (size_t)e * (F / 4) + lane);
        int dst  = nbrs[2 * e];
        float* m = msg + (size_t)dst * F + lane * 4;
        atomicAdd(m + 0, v.x);
        atomicAdd(m + 1, v.y);
        atomicAdd(m + 2, v.z);
        atomicAdd(m + 3, v.w);
    }
}

// ---------------------------------------------------------------------------
// Fused MLP: out = relu([r | msg] @ W1) @ W2, per block of BM=32 node rows.
// 256 threads. LDS (80 KB -> 2 blocks/CU):
//   region0 floats [0,16384): phase1 = W1 tile [KT][512]; phase2 = hid [32][512]
//   region1 floats [16384,20480): phase1 = catsT [KT][36]; phase2 = W2 tile [KT][256]
// NOTE: msg MAY alias out (ws fallback). Safe: each block reads only its own
// 32 msg rows (phase 1) and writes the same rows only after phase 2.
// ---------------------------------------------------------------------------
__global__ __launch_bounds__(256, 2) void mlp_kernel(
        const float* __restrict__ r,
        const float* msg,
        const float* __restrict__ W1,
        const float* __restrict__ W2,
        float* out,
        int n_nodes) {
    __shared__ float smem[20480];   // 80 KB
    float* w1t   = smem;            // [KT][512]
    float* hid   = smem;            // [32][512] (aliases w1t, disjoint in time)
    float* catsT = smem + 16384;    // [KT][36]  (transposed cat tile, 16B-aligned rows)
    float* w2t   = smem + 16384;    // [KT][256] (aliases catsT, disjoint in time)

    const int tid  = threadIdx.x;
    const int tx   = tid & 31;      // 32 col-groups
    const int ty   = tid >> 5;      // 8 row-groups of 4 rows
    const int base = blockIdx.x * BM;

    // ---------------- phase 1: hidden = relu(cat @ W1) ----------------
    float acc[4][16];
#pragma unroll
    for (int i = 0; i < 4; ++i)
#pragma unroll
        for (int j = 0; j < 16; ++j) acc[i][j] = 0.0f;

    const int lrow = tid >> 3;           // 0..31 (cat-load row)
    const int lkc  = (tid & 7) * 2;      // 0..14 even (cat-load k pair)
    const int wkr  = tid >> 4;           // 0..15 (w-load row)
    const int wc4  = (tid & 15) * 4;     // w-load col

    for (int kt = 0; kt < K1; kt += KT) {
        // load cat tile, stored transposed: catsT[k][row]
        {
            float2 v = make_float2(0.0f, 0.0f);
            int node = base + lrow;
            int gk   = kt + lkc;         // even; gk and gk+1 on same side of F
            if (node < n_nodes) {
                const float* src = (gk < F) ? (r + (size_t)node * F + gk)
                                            : (msg + (size_t)node * F + (gk - F));
                v = *reinterpret_cast<const float2*>(src);
            }
            catsT[lkc * 36 + lrow]       = v.x;
            catsT[(lkc + 1) * 36 + lrow] = v.y;
        }
        // load W1 tile [KT][512]
        {
            const float* src = W1 + (size_t)(kt + wkr) * K1 + wc4;
            float* dst = w1t + wkr * 512 + wc4;
#pragma unroll
            for (int j = 0; j < 8; ++j) {
                *reinterpret_cast<float4*>(dst + 64 * j) =
                    *reinterpret_cast<const float4*>(src + 64 * j);
            }
        }
        __syncthreads();
#pragma unroll
        for (int kk = 0; kk < KT; ++kk) {
            // A: 4 rows (ty*4..ty*4+3) at k=kk -> one aligned b128, broadcast
            const float4 a4 = *reinterpret_cast<const float4*>(catsT + kk * 36 + ty * 4);
            const float* wrow = w1t + kk * 512 + tx * 4;
            float4 b0 = *reinterpret_cast<const float4*>(wrow + 0);
            float4 b1 = *reinterpret_cast<const float4*>(wrow + 128);
            float4 b2 = *reinterpret_cast<const float4*>(wrow + 256);
            float4 b3 = *reinterpret_cast<const float4*>(wrow + 384);
            const float bs[16] = {b0.x, b0.y, b0.z, b0.w, b1.x, b1.y, b1.z, b1.w,
                                  b2.x, b2.y, b2.z, b2.w, b3.x, b3.y, b3.z, b3.w};
            const float as[4] = {a4.x, a4.y, a4.z, a4.w};
#pragma unroll
            for (int i = 0; i < 4; ++i)
#pragma unroll
                for (int j = 0; j < 16; ++j) acc[i][j] = fmaf(as[i], bs[j], acc[i][j]);
        }
        __syncthreads();
    }

    // ---------------- relu + stash hidden tile in LDS ----------------
#pragma unroll
    for (int i = 0; i < 4; ++i) {
#pragma unroll
        for (int g = 0; g < 4; ++g) {
            float4 v;
            v.x = fmaxf(acc[i][g * 4 + 0], 0.0f);
            v.y = fmaxf(acc[i][g * 4 + 1], 0.0f);
            v.z = fmaxf(acc[i][g * 4 + 2], 0.0f);
            v.w = fmaxf(acc[i][g * 4 + 3], 0.0f);
            *reinterpret_cast<float4*>(hid + (ty * 4 + i) * 512 + tx * 4 + 128 * g) = v;
        }
    }
    // hid writes are fenced from reads by the barrier inside the first
    // phase-2 iteration.

    // ---------------- phase 2: out = hid @ W2 ----------------
    float acc2[4][8];
#pragma unroll
    for (int i = 0; i < 4; ++i)
#pragma unroll
        for (int j = 0; j < 8; ++j) acc2[i][j] = 0.0f;

    for (int kt2 = 0; kt2 < HDIM; kt2 += KT) {
        // load W2 tile [KT][256]
        {
            const float* src = W2 + (size_t)(kt2 + wkr) * FOUT + wc4;
            float* dst = w2t + wkr * 256 + wc4;
#pragma unroll
            for (int j = 0; j < 4; ++j) {
                *reinterpret_cast<float4*>(dst + 64 * j) =
                    *reinterpret_cast<const float4*>(src + 64 * j);
            }
        }
        __syncthreads();
#pragma unroll
        for (int kk = 0; kk < KT; ++kk) {
            float a0 = hid[(ty * 4 + 0) * 512 + kt2 + kk];
            float a1 = hid[(ty * 4 + 1) * 512 + kt2 + kk];
            float a2 = hid[(ty * 4 + 2) * 512 + kt2 + kk];
            float a3 = hid[(ty * 4 + 3) * 512 + kt2 + kk];
            const float* wrow = w2t + kk * 256 + tx * 4;
            float4 b0 = *reinterpret_cast<const float4*>(wrow + 0);
            float4 b1 = *reinterpret_cast<const float4*>(wrow + 128);
            const float bs[8] = {b0.x, b0.y, b0.z, b0.w, b1.x, b1.y, b1.z, b1.w};
            const float as[4] = {a0, a1, a2, a3};
#pragma unroll
            for (int i = 0; i < 4; ++i)
#pragma unroll
                for (int j = 0; j < 8; ++j) acc2[i][j] = fmaf(as[i], bs[j], acc2[i][j]);
        }
        __syncthreads();
    }

    // ---------------- store out ----------------
#pragma unroll
    for (int i = 0; i < 4; ++i) {
        int node = base + ty * 4 + i;
        if (node < n_nodes) {
#pragma unroll
            for (int g = 0; g < 2; ++g) {
                float4 v;
                v.x = acc2[i][g * 4 + 0];
                v.y = acc2[i][g * 4 + 1];
                v.z = acc2[i][g * 4 + 2];
                v.w = acc2[i][g * 4 + 3];
                *reinterpret_cast<float4*>(out + (size_t)node * FOUT + tx * 4 + 128 * g) = v;
            }
        }
    }
}

// ---------------------------------------------------------------------------
extern "C" void kernel_launch(void* const* d_in, const int* in_sizes, int n_in,
                              void* d_out, int out_size, void* d_ws, size_t ws_size,
                              hipStream_t stream) {
    const float* r    = (const float*)d_in[0];
    const float* h    = (const float*)d_in[1];
    const int*   nbrs = (const int*)d_in[2];
    const float* W1   = (const float*)d_in[3];
    const float* W2   = (const float*)d_in[4];
    float* out = (float*)d_out;

    const int n_nodes = in_sizes[0] / F;
    const int n_edges = in_sizes[1] / F;

    // msg accumulator [n_nodes, F]; fall back to aliasing d_out if ws too small
    const size_t msg_bytes = (size_t)n_nodes * F * sizeof(float);
    float* msg = (ws_size >= msg_bytes) ? (float*)d_ws : out;

    (void)hipMemsetAsync(msg, 0, msg_bytes, stream);

    // scatter-add edge features into nodes
    {
        dim3 grid(2048), block(256);
        scatter_kernel<<<grid, block, 0, stream>>>(
            (const floatx4*)h, nbrs, msg, n_edges);
    }

    // fused concat + GEMM1 + relu + GEMM2
    {
        dim3 grid((n_nodes + BM - 1) / BM), block(256);
        mlp_kernel<<<grid, block, 0, stream>>>(r, msg, W1, W2, out, n_nodes);
    }
}